// Round 1
// baseline (31.244 us; speedup 1.0000x reference)
//
#include <hip/hip_runtime.h>

#define BB 16
#define NN 2048
#define DD 3
#define TT 64
#define RR 64

// Robustly read `scale` whether the harness passed int32/int64 or float32.
__device__ inline float load_scale(const void* p) {
    int i = *(const int*)p;
    if (i > 0 && i < (1 << 23)) return (float)i;   // plausible integer
    return *(const float*)p;                       // else it was float bits
}

__global__ __launch_bounds__(256, 4)
void ect_kernel(const float* __restrict__ x, const float* __restrict__ v,
                const float* __restrict__ lin, const void* __restrict__ scale_p,
                float* __restrict__ out) {
    __shared__ float s_bn[NN];      // K * (x . v_t), pre-scaled
    __shared__ float s_part[256];   // cross-wave reduction

    const int bt   = blockIdx.x;        // b*64 + t
    const int b    = bt >> 6;
    const int t    = bt & 63;
    const int tid  = threadIdx.x;
    const int lane = tid & 63;          // = r
    const int wave = tid >> 6;          // n-phase (mod 4)

    const float K = load_scale(scale_p) * 1.44269504088896340736f; // scale*log2(e)

    const float v0 = v[t];
    const float v1 = v[TT + t];
    const float v2 = v[2 * TT + t];

    // ---- phase 1: projection, pre-scaled by K, into LDS ----
    const float* xb = x + (size_t)b * NN * DD;
    #pragma unroll
    for (int k = 0; k < NN / 256; ++k) {
        int n = tid + k * 256;
        float x0 = xb[n * 3 + 0];
        float x1 = xb[n * 3 + 1];
        float x2 = xb[n * 3 + 2];
        s_bn[n] = K * (x0 * v0 + x1 * v1 + x2 * v2);
    }
    __syncthreads();

    // ---- phase 2: lane r sums sigmoid over its wave's n-subset ----
    // sigmoid(scale*(lin[r]-nh)) = 1 / (1 + exp2(K*nh - K*lin[r]))
    const float a = K * lin[lane];
    float acc0 = 0.f, acc1 = 0.f, acc2 = 0.f, acc3 = 0.f;
    #pragma unroll 4
    for (int k = 0; k < NN / 16; ++k) {
        int nb = wave + 16 * k;
        float bn0 = s_bn[nb +  0];
        float bn1 = s_bn[nb +  4];
        float bn2 = s_bn[nb +  8];
        float bn3 = s_bn[nb + 12];
        acc0 += __builtin_amdgcn_rcpf(1.f + __builtin_amdgcn_exp2f(bn0 - a));
        acc1 += __builtin_amdgcn_rcpf(1.f + __builtin_amdgcn_exp2f(bn1 - a));
        acc2 += __builtin_amdgcn_rcpf(1.f + __builtin_amdgcn_exp2f(bn2 - a));
        acc3 += __builtin_amdgcn_rcpf(1.f + __builtin_amdgcn_exp2f(bn3 - a));
    }
    float acc = (acc0 + acc1) + (acc2 + acc3);

    s_part[tid] = acc;
    __syncthreads();
    if (tid < 64) {
        float s = s_part[tid] + s_part[tid + 64] + s_part[tid + 128] + s_part[tid + 192];
        out[((size_t)b * RR + tid) * TT + t] = s;   // out[b, r, t]
    }
}

extern "C" void kernel_launch(void* const* d_in, const int* in_sizes, int n_in,
                              void* d_out, int out_size, void* d_ws, size_t ws_size,
                              hipStream_t stream) {
    const float* x    = (const float*)d_in[0];
    const float* v    = (const float*)d_in[1];
    const float* lin  = (const float*)d_in[2];
    const void*  scal = d_in[3];
    float* out = (float*)d_out;

    dim3 grid(BB * TT);   // 1024 blocks: one per (b, t)
    dim3 block(256);
    ect_kernel<<<grid, block, 0, stream>>>(x, v, lin, scal, out);
}